// Round 8
// baseline (321.186 us; speedup 1.0000x reference)
//
#include <hip/hip_runtime.h>

// ---------------------------------------------------------------------------
// GCN: x1 = relu(Ahat @ (fts@W1) + b1); x2 = relu(Ahat @ (x1@W2) + b2);
//      out = x2@Wc + bc.  Ahat = D^-1/2 (A + I) D^-1/2.
// d_out = [out (N*16) | x2 (N*128)] fp32.
// R2: hierarchical scan. R3: gather prescale+unroll. R4: MFMA fp16 GEMMs.
// R5/R6: slot-capture CSR build. R7: 8-replica degree counters.
// R8: agg was MLP-limited (2.7 TB/s on 83MB structural traffic) — 2 waves
//     per node (edge-split, LDS combine) doubles outstanding gathers.
//     Launch diet: k_prep fuses zero+wswz+bperm; scan2 folded into scan3
//     (per-block redundant reduction of <=196 block sums). 17 -> 10 launches.
// ---------------------------------------------------------------------------

#define IN_DIM 256
#define HID 128
#define OUT_DIM 16
#define SCAN_B 256
#define NREP 8

typedef _Float16 half8  __attribute__((ext_vector_type(8)));
typedef _Float16 half2v __attribute__((ext_vector_type(2)));
typedef float    floatx4 __attribute__((ext_vector_type(4)));

__device__ __forceinline__ void wswz_one(const float* W, _Float16* Bsw, int o, int permK) {
    int j    = o & 7;
    int lane = (o >> 3) & 63;
    int t    = (o >> 9) & 7;
    int c    = o >> 12;
    int k = c * 32 + ((lane >> 4) << 3) + j;
    if (permK) k = ((k & 7) << 4) + (k >> 3);
    int ncol = t * 16 + (lane & 15);
    Bsw[o] = (_Float16)W[k * 128 + ncol];
}

// Fused prep: zero rep planes; swizzle W1,W2 -> fp16 fragment order; permute biases.
__global__ void k_prep(int* __restrict__ rep, int nrepN,
                       const float* __restrict__ W1, _Float16* __restrict__ Bsw1,
                       const float* __restrict__ W2, _Float16* __restrict__ Bsw2,
                       const float* __restrict__ b1, float* __restrict__ bp1,
                       const float* __restrict__ b2, float* __restrict__ bp2) {
    int t = blockIdx.x * blockDim.x + threadIdx.x;
    int z4 = nrepN >> 2;
    int zr = z4 + (nrepN & 3);
    if (t < z4) { ((int4*)rep)[t] = make_int4(0, 0, 0, 0); return; }
    if (t < zr) { rep[4 * z4 + (t - z4)] = 0; return; }
    int o = t - zr;
    if (o < IN_DIM * HID) { wswz_one(W1, Bsw1, o, 0); return; }
    o -= IN_DIM * HID;
    if (o < HID * HID) { wswz_one(W2, Bsw2, o, 1); return; }
    o -= HID * HID;
    if (o < HID) { bp1[o] = b1[((o & 7) << 4) + (o >> 3)]; return; }
    o -= HID;
    if (o < HID) { bp2[o] = b2[((o & 7) << 4) + (o >> 3)]; return; }
}

// Thread i owns edges 8i..8i+7; edge 8i+k bumps replica plane k.
__global__ void k_count(const int* __restrict__ dst, int* __restrict__ rep,
                        int* __restrict__ slot, int nN, int e8, int e) {
    int i = blockIdx.x * blockDim.x + threadIdx.x;
    if (i < e8) {
        int4 d0 = ((const int4*)dst)[2 * i];
        int4 d1 = ((const int4*)dst)[2 * i + 1];
        int4 s0, s1;
        s0.x = atomicAdd(&rep[0 * nN + d0.x], 1);
        s0.y = atomicAdd(&rep[1 * nN + d0.y], 1);
        s0.z = atomicAdd(&rep[2 * nN + d0.z], 1);
        s0.w = atomicAdd(&rep[3 * nN + d0.w], 1);
        s1.x = atomicAdd(&rep[4 * nN + d1.x], 1);
        s1.y = atomicAdd(&rep[5 * nN + d1.y], 1);
        s1.z = atomicAdd(&rep[6 * nN + d1.z], 1);
        s1.w = atomicAdd(&rep[7 * nN + d1.w], 1);
        ((int4*)slot)[2 * i]     = s0;
        ((int4*)slot)[2 * i + 1] = s1;
    }
    int base = e8 * 8;
    int t = blockIdx.x * blockDim.x + threadIdx.x;
    if (t < e - base) {
        int j = base + t;
        slot[j] = atomicAdd(&rep[(j & 7) * nN + dst[j]], 1);
    }
}

// Planes -> per-node exclusive bases (in-place); node totals -> deg;
// per-block scan of totals; block total -> bsum.
__global__ __launch_bounds__(SCAN_B) void k_scan1(int* __restrict__ rep,
                                                  int* __restrict__ deg,
                                                  int* __restrict__ row_ptr,
                                                  int* __restrict__ bsum,
                                                  int nN, int n) {
    __shared__ int tmp[SCAN_B];
    int tid = threadIdx.x;
    int i = blockIdx.x * SCAN_B + tid;
    int c = 0;
    if (i < n) {
        #pragma unroll
        for (int r = 0; r < NREP; ++r) {
            int t = rep[r * nN + i];
            rep[r * nN + i] = c;
            c += t;
        }
        deg[i] = c;
    }
    tmp[tid] = c;
    __syncthreads();
    #pragma unroll
    for (int off = 1; off < SCAN_B; off <<= 1) {
        int v = (tid >= off) ? tmp[tid - off] : 0;
        __syncthreads();
        tmp[tid] += v;
        __syncthreads();
    }
    if (i < n) row_ptr[i] = tmp[tid] - c;          // local exclusive
    if (tid == SCAN_B - 1) bsum[blockIdx.x] = tmp[tid];  // raw block total
}

// Finalize: base = sum(bsum[0..blockIdx-1]) (redundant per-block reduce);
// row_ptr/dinv; bake absolute base into planes.
__global__ __launch_bounds__(SCAN_B) void k_scan3(int* __restrict__ row_ptr,
                                                  const int* __restrict__ bsum,
                                                  const int* __restrict__ deg,
                                                  float* __restrict__ dinv,
                                                  int* __restrict__ rep,
                                                  int nN, int n, int e) {
    __shared__ int red[SCAN_B];
    int tid = threadIdx.x;
    int acc = 0;
    for (int j = tid; j < blockIdx.x; j += SCAN_B) acc += bsum[j];
    red[tid] = acc;
    __syncthreads();
    #pragma unroll
    for (int off = SCAN_B / 2; off >= 1; off >>= 1) {
        if (tid < off) red[tid] += red[tid + off];
        __syncthreads();
    }
    int base = red[0];
    int i = blockIdx.x * SCAN_B + tid;
    if (i < n) {
        int rp = row_ptr[i] + base;
        row_ptr[i] = rp;
        dinv[i] = rsqrtf((float)(deg[i] + 1));   // +1 self-loop
        #pragma unroll
        for (int r = 0; r < NREP; ++r) rep[r * nN + i] += rp;
    }
    if (i == 0) row_ptr[n] = e;
}

// Atomic-free scatter: col[rep[k][dst] + slot] = src.
__global__ void k_fill(const int* __restrict__ src, const int* __restrict__ dst,
                       const int* __restrict__ slot, const int* __restrict__ rep,
                       int* __restrict__ col, int nN, int e8, int e) {
    int i = blockIdx.x * blockDim.x + threadIdx.x;
    if (i < e8) {
        int4 v0 = ((const int4*)src)[2 * i];
        int4 v1 = ((const int4*)src)[2 * i + 1];
        int4 d0 = ((const int4*)dst)[2 * i];
        int4 d1 = ((const int4*)dst)[2 * i + 1];
        int4 s0 = ((const int4*)slot)[2 * i];
        int4 s1 = ((const int4*)slot)[2 * i + 1];
        col[rep[0 * nN + d0.x] + s0.x] = v0.x;
        col[rep[1 * nN + d0.y] + s0.y] = v0.y;
        col[rep[2 * nN + d0.z] + s0.z] = v0.z;
        col[rep[3 * nN + d0.w] + s0.w] = v0.w;
        col[rep[4 * nN + d1.x] + s1.x] = v1.x;
        col[rep[5 * nN + d1.y] + s1.y] = v1.y;
        col[rep[6 * nN + d1.z] + s1.z] = v1.z;
        col[rep[7 * nN + d1.w] + s1.w] = v1.w;
    }
    int base = e8 * 8;
    int t = blockIdx.x * blockDim.x + threadIdx.x;
    if (t < e - base) {
        int j = base + t;
        col[rep[(j & 7) * nN + dst[j]] + slot[j]] = src[j];
    }
}

// Cb[n,128](fp16, pi-permuted cols) = dinv[row] * (A[n,K] @ W[K,128]).
template<bool A32>
__global__ __launch_bounds__(256) void k_gemm_mfma(const void* __restrict__ Av,
                                                   const _Float16* __restrict__ Bsw,
                                                   _Float16* __restrict__ Cb,
                                                   const float* __restrict__ dinv,
                                                   int n, int K) {
    int tid   = threadIdx.x;
    int w     = tid >> 6;
    int ln    = tid & 63;
    int lane16 = ln & 15;
    int quad  = ln >> 4;
    int mrow  = blockIdx.x * 64 + w * 16 + lane16;
    int mload = mrow < n ? mrow : n - 1;
    int nchunk = K >> 5;

    floatx4 acc[8];
    #pragma unroll
    for (int t = 0; t < 8; ++t) acc[t] = (floatx4){0.f, 0.f, 0.f, 0.f};

    for (int c = 0; c < nchunk; ++c) {
        half8 a;
        if constexpr (A32) {
            const float* ap = (const float*)Av + (size_t)mload * K + c * 32 + quad * 8;
            float4 v0 = *(const float4*)ap;
            float4 v1 = *(const float4*)(ap + 4);
            a[0] = (_Float16)v0.x; a[1] = (_Float16)v0.y;
            a[2] = (_Float16)v0.z; a[3] = (_Float16)v0.w;
            a[4] = (_Float16)v1.x; a[5] = (_Float16)v1.y;
            a[6] = (_Float16)v1.z; a[7] = (_Float16)v1.w;
        } else {
            const _Float16* ap = (const _Float16*)Av + (size_t)mload * K + c * 32 + quad * 8;
            a = *(const half8*)ap;
        }
        const _Float16* bp = Bsw + ((size_t)(c * 8) * 64 + ln) * 8;
        #pragma unroll
        for (int t = 0; t < 8; ++t) {
            half8 b = *(const half8*)(bp + (size_t)t * 512);
            acc[t] = __builtin_amdgcn_mfma_f32_16x16x32_f16(a, b, acc[t], 0, 0, 0);
        }
    }

    int rbase = blockIdx.x * 64 + w * 16 + quad * 4;
    #pragma unroll
    for (int r = 0; r < 4; ++r) {
        int R = rbase + r;
        if (R < n) {
            float d = dinv[R];
            half8 o;
            #pragma unroll
            for (int t = 0; t < 8; ++t) o[t] = (_Float16)(acc[t][r] * d);
            *(half8*)(Cb + (size_t)R * 128 + lane16 * 8) = o;
        }
    }
}

// 2 nodes/block, 2 waves/node (edge-split halves), LDS combine.
template<bool OUT16>
__global__ __launch_bounds__(256) void k_agg(const _Float16* __restrict__ xwb,
                                             const float* __restrict__ dinv,
                                             const int* __restrict__ row_ptr,
                                             const int* __restrict__ col,
                                             const float* __restrict__ bp,
                                             void* __restrict__ hout, int n) {
    __shared__ float part[2][128];
    int tid  = threadIdx.x;
    int wave = tid >> 6;
    int ln   = tid & 63;
    int nl   = wave >> 1;            // node index within block (0,1)
    int half = wave & 1;
    int i = blockIdx.x * 2 + nl;

    int e0 = 0, e1 = 0;
    if (i < n) { e0 = row_ptr[i]; e1 = row_ptr[i + 1]; }
    int len   = e1 - e0;
    int hlen0 = (len + 1) >> 1;
    int b0 = half ? (e0 + hlen0) : e0;
    int b1 = half ? e1 : (e0 + hlen0);

    float ax = 0.f, ay = 0.f;
    int e = b0;
    for (; e + 8 <= b1; e += 8) {
        int s0 = col[e + 0], s1 = col[e + 1], s2 = col[e + 2], s3 = col[e + 3];
        int s4 = col[e + 4], s5 = col[e + 5], s6 = col[e + 6], s7 = col[e + 7];
        half2v u0 = *(const half2v*)(xwb + (size_t)s0 * 128 + ln * 2);
        half2v u1 = *(const half2v*)(xwb + (size_t)s1 * 128 + ln * 2);
        half2v u2 = *(const half2v*)(xwb + (size_t)s2 * 128 + ln * 2);
        half2v u3 = *(const half2v*)(xwb + (size_t)s3 * 128 + ln * 2);
        half2v u4 = *(const half2v*)(xwb + (size_t)s4 * 128 + ln * 2);
        half2v u5 = *(const half2v*)(xwb + (size_t)s5 * 128 + ln * 2);
        half2v u6 = *(const half2v*)(xwb + (size_t)s6 * 128 + ln * 2);
        half2v u7 = *(const half2v*)(xwb + (size_t)s7 * 128 + ln * 2);
        ax += (float)u0[0] + (float)u1[0] + (float)u2[0] + (float)u3[0]
            + (float)u4[0] + (float)u5[0] + (float)u6[0] + (float)u7[0];
        ay += (float)u0[1] + (float)u1[1] + (float)u2[1] + (float)u3[1]
            + (float)u4[1] + (float)u5[1] + (float)u6[1] + (float)u7[1];
    }
    for (; e < b1; ++e) {
        int s = col[e];
        half2v u = *(const half2v*)(xwb + (size_t)s * 128 + ln * 2);
        ax += (float)u[0];
        ay += (float)u[1];
    }
    if (half == 1) {
        part[nl][2 * ln]     = ax;
        part[nl][2 * ln + 1] = ay;
    }
    __syncthreads();
    if (half == 0 && i < n) {
        ax += part[nl][2 * ln];
        ay += part[nl][2 * ln + 1];
        {   // self-loop
            half2v u = *(const half2v*)(xwb + (size_t)i * 128 + ln * 2);
            ax += (float)u[0];
            ay += (float)u[1];
        }
        float di = dinv[i];
        float2 b = *(const float2*)(bp + ln * 2);
        float ox = fmaxf(fmaf(di, ax, b.x), 0.f);
        float oy = fmaxf(fmaf(di, ay, b.y), 0.f);
        if constexpr (OUT16) {
            half2v o; o[0] = (_Float16)ox; o[1] = (_Float16)oy;
            *(half2v*)((_Float16*)hout + (size_t)i * 128 + ln * 2) = o;
        } else {
            float* hf = (float*)hout;
            int p0 = 2 * ln, p1 = 2 * ln + 1;
            int c0 = ((p0 & 7) << 4) + (p0 >> 3);
            int c1 = ((p1 & 7) << 4) + (p1 >> 3);
            hf[(size_t)i * 128 + c0] = ox;
            hf[(size_t)i * 128 + c1] = oy;
        }
    }
}

// out[n,16] = h2[n,128] @ Wc[128,16] + bc. (h2 fp32, un-permuted.)
__global__ __launch_bounds__(256) void k_out(const float* __restrict__ h2,
                                             const float* __restrict__ Wc,
                                             const float* __restrict__ bc,
                                             float* __restrict__ out, int n) {
    __shared__ float Ws[128 * 16];
    __shared__ float bs[16];
    __shared__ float hs[16][128];
    int tid = threadIdx.x;
    for (int t = tid; t < 128 * 16; t += 256) Ws[t] = Wc[t];
    if (tid < 16) bs[tid] = bc[tid];
    int r0 = blockIdx.x * 16;
    {
        int r = tid >> 4;
        int c = (tid & 15) * 8;
        int row = r0 + r;
        if (row < n) {
            const float* hp = h2 + (size_t)row * 128 + c;
            *(float4*)&hs[r][c]     = *(const float4*)hp;
            *(float4*)&hs[r][c + 4] = *(const float4*)(hp + 4);
        }
    }
    __syncthreads();
    int ti = tid >> 4, j = tid & 15;
    float acc = bs[j];
    #pragma unroll 8
    for (int k = 0; k < 128; ++k) acc = fmaf(hs[ti][k], Ws[k * 16 + j], acc);
    int row = r0 + ti;
    if (row < n) out[(size_t)row * 16 + j] = acc;
}

static inline size_t align256(size_t x) { return (x + 255) & ~(size_t)255; }

extern "C" void kernel_launch(void* const* d_in, const int* in_sizes, int n_in,
                              void* d_out, int out_size, void* d_ws, size_t ws_size,
                              hipStream_t stream) {
    const float* fts = (const float*)d_in[0];
    const int*   ei  = (const int*)d_in[1];
    const float* W1  = (const float*)d_in[2];
    const float* b1  = (const float*)d_in[3];
    const float* W2  = (const float*)d_in[4];
    const float* b2  = (const float*)d_in[5];
    const float* Wc  = (const float*)d_in[6];
    const float* bc  = (const float*)d_in[7];

    const int N = in_sizes[0] / IN_DIM;     // 50000
    const int E = in_sizes[1] / 2;          // 800000
    const int* src = ei;
    const int* dst = ei + E;

    char* p = (char*)d_ws;
    int* rep      = (int*)p;               p += align256(sizeof(int) * NREP * N);
    int* deg      = (int*)p;               p += align256(sizeof(int) * N);
    int* row_ptr  = (int*)p;               p += align256(sizeof(int) * (N + 1));
    float* dinv   = (float*)p;             p += align256(sizeof(float) * N);
    int* slot     = (int*)p;               p += align256(sizeof(int) * E);
    int* col      = (int*)p;               p += align256(sizeof(int) * E);
    int* bsum     = (int*)p;               p += align256(sizeof(int) * 512);
    _Float16* Bsw1 = (_Float16*)p;         p += align256(sizeof(_Float16) * IN_DIM * HID);
    _Float16* Bsw2 = (_Float16*)p;         p += align256(sizeof(_Float16) * HID * HID);
    float* bp1    = (float*)p;             p += align256(sizeof(float) * HID);
    float* bp2    = (float*)p;             p += align256(sizeof(float) * HID);
    _Float16* xwb = (_Float16*)p;          p += align256(sizeof(_Float16) * (size_t)N * HID);
    _Float16* h1  = (_Float16*)p;          p += align256(sizeof(_Float16) * (size_t)N * HID);

    float* out = (float*)d_out;                   // [N,16]
    float* h2  = (float*)d_out + (size_t)N * 16;  // [N,128]

    const int T = 256;
    const int E8 = E / 8;
    dim3 gE8((E8 + T - 1) / T);
    const int nScanB = (N + SCAN_B - 1) / SCAN_B;

    // Fused prep (rep zero + W swizzles + bias perms)
    const int nrepN = NREP * N;
    const int zr = (nrepN >> 2) + (nrepN & 3);
    const int prepTot = zr + IN_DIM * HID + HID * HID + 2 * HID;
    k_prep<<<(prepTot + T - 1) / T, T, 0, stream>>>(rep, nrepN, W1, Bsw1, W2, Bsw2,
                                                    b1, bp1, b2, bp2);
    // Graph structure
    k_count<<<gE8, T, 0, stream>>>(dst, rep, slot, N, E8, E);
    k_scan1<<<nScanB, SCAN_B, 0, stream>>>(rep, deg, row_ptr, bsum, N, N);
    k_scan3<<<nScanB, SCAN_B, 0, stream>>>(row_ptr, bsum, deg, dinv, rep, N, N, E);
    k_fill<<<gE8, T, 0, stream>>>(src, dst, slot, rep, col, N, E8, E);

    dim3 gGemm((N + 63) / 64);
    dim3 gAgg((N + 1) / 2);

    // Layer 1
    k_gemm_mfma<true><<<gGemm, T, 0, stream>>>(fts, Bsw1, xwb, dinv, N, IN_DIM);
    k_agg<true><<<gAgg, T, 0, stream>>>(xwb, dinv, row_ptr, col, bp1, h1, N);
    // Layer 2
    k_gemm_mfma<false><<<gGemm, T, 0, stream>>>(h1, Bsw2, xwb, dinv, N, HID);
    k_agg<false><<<gAgg, T, 0, stream>>>(xwb, dinv, row_ptr, col, bp2, h2, N);
    // Classifier
    k_out<<<(N + 15) / 16, T, 0, stream>>>(h2, Wc, bc, out, N);
}

// Round 9
// 268.211 us; speedup vs baseline: 1.1975x; 1.1975x over previous
//
#include <hip/hip_runtime.h>

// ---------------------------------------------------------------------------
// GCN: x1 = relu(Ahat @ (fts@W1) + b1); x2 = relu(Ahat @ (x1@W2) + b2);
//      out = x2@Wc + bc.  Ahat = D^-1/2 (A + I) D^-1/2.
// d_out = [out (N*16) | x2 (N*128)] fp32.
// R2: hierarchical scan. R3: gather prescale+unroll. R4: MFMA fp16 GEMMs.
// R5/R6: slot-capture CSR build. R7: 8-replica counters. R8: launch diet
// (k_prep, folded scan); edge-split agg REGRESSED (barrier-coupled waves).
// R9: agg reverted to barrier-free 1 wave/node, widened to 16 lanes/row
//     dwordx4 gathers: 4 edges per load instr x4 unroll = 16 rows (4KB) in
//     flight/wave vs R7's 8 (2KB). shfl_xor(16,32) butterfly combine.
// ---------------------------------------------------------------------------

#define IN_DIM 256
#define HID 128
#define OUT_DIM 16
#define SCAN_B 256
#define NREP 8

typedef _Float16 half8  __attribute__((ext_vector_type(8)));
typedef float    floatx4 __attribute__((ext_vector_type(4)));

__device__ __forceinline__ void wswz_one(const float* W, _Float16* Bsw, int o, int permK) {
    int j    = o & 7;
    int lane = (o >> 3) & 63;
    int t    = (o >> 9) & 7;
    int c    = o >> 12;
    int k = c * 32 + ((lane >> 4) << 3) + j;
    if (permK) k = ((k & 7) << 4) + (k >> 3);
    int ncol = t * 16 + (lane & 15);
    Bsw[o] = (_Float16)W[k * 128 + ncol];
}

// Fused prep: zero rep planes; swizzle W1,W2 -> fp16 fragment order; permute biases.
__global__ void k_prep(int* __restrict__ rep, int nrepN,
                       const float* __restrict__ W1, _Float16* __restrict__ Bsw1,
                       const float* __restrict__ W2, _Float16* __restrict__ Bsw2,
                       const float* __restrict__ b1, float* __restrict__ bp1,
                       const float* __restrict__ b2, float* __restrict__ bp2) {
    int t = blockIdx.x * blockDim.x + threadIdx.x;
    int z4 = nrepN >> 2;
    int zr = z4 + (nrepN & 3);
    if (t < z4) { ((int4*)rep)[t] = make_int4(0, 0, 0, 0); return; }
    if (t < zr) { rep[4 * z4 + (t - z4)] = 0; return; }
    int o = t - zr;
    if (o < IN_DIM * HID) { wswz_one(W1, Bsw1, o, 0); return; }
    o -= IN_DIM * HID;
    if (o < HID * HID) { wswz_one(W2, Bsw2, o, 1); return; }
    o -= HID * HID;
    if (o < HID) { bp1[o] = b1[((o & 7) << 4) + (o >> 3)]; return; }
    o -= HID;
    if (o < HID) { bp2[o] = b2[((o & 7) << 4) + (o >> 3)]; return; }
}

// Thread i owns edges 8i..8i+7; edge 8i+k bumps replica plane k.
__global__ void k_count(const int* __restrict__ dst, int* __restrict__ rep,
                        int* __restrict__ slot, int nN, int e8, int e) {
    int i = blockIdx.x * blockDim.x + threadIdx.x;
    if (i < e8) {
        int4 d0 = ((const int4*)dst)[2 * i];
        int4 d1 = ((const int4*)dst)[2 * i + 1];
        int4 s0, s1;
        s0.x = atomicAdd(&rep[0 * nN + d0.x], 1);
        s0.y = atomicAdd(&rep[1 * nN + d0.y], 1);
        s0.z = atomicAdd(&rep[2 * nN + d0.z], 1);
        s0.w = atomicAdd(&rep[3 * nN + d0.w], 1);
        s1.x = atomicAdd(&rep[4 * nN + d1.x], 1);
        s1.y = atomicAdd(&rep[5 * nN + d1.y], 1);
        s1.z = atomicAdd(&rep[6 * nN + d1.z], 1);
        s1.w = atomicAdd(&rep[7 * nN + d1.w], 1);
        ((int4*)slot)[2 * i]     = s0;
        ((int4*)slot)[2 * i + 1] = s1;
    }
    int base = e8 * 8;
    int t = blockIdx.x * blockDim.x + threadIdx.x;
    if (t < e - base) {
        int j = base + t;
        slot[j] = atomicAdd(&rep[(j & 7) * nN + dst[j]], 1);
    }
}

// Planes -> per-node exclusive bases (in-place); node totals -> deg;
// per-block scan of totals; block total -> bsum.
__global__ __launch_bounds__(SCAN_B) void k_scan1(int* __restrict__ rep,
                                                  int* __restrict__ deg,
                                                  int* __restrict__ row_ptr,
                                                  int* __restrict__ bsum,
                                                  int nN, int n) {
    __shared__ int tmp[SCAN_B];
    int tid = threadIdx.x;
    int i = blockIdx.x * SCAN_B + tid;
    int c = 0;
    if (i < n) {
        #pragma unroll
        for (int r = 0; r < NREP; ++r) {
            int t = rep[r * nN + i];
            rep[r * nN + i] = c;
            c += t;
        }
        deg[i] = c;
    }
    tmp[tid] = c;
    __syncthreads();
    #pragma unroll
    for (int off = 1; off < SCAN_B; off <<= 1) {
        int v = (tid >= off) ? tmp[tid - off] : 0;
        __syncthreads();
        tmp[tid] += v;
        __syncthreads();
    }
    if (i < n) row_ptr[i] = tmp[tid] - c;
    if (tid == SCAN_B - 1) bsum[blockIdx.x] = tmp[tid];
}

// Finalize: base = sum(bsum[0..blockIdx-1]); row_ptr/dinv; bake bases into planes.
__global__ __launch_bounds__(SCAN_B) void k_scan3(int* __restrict__ row_ptr,
                                                  const int* __restrict__ bsum,
                                                  const int* __restrict__ deg,
                                                  float* __restrict__ dinv,
                                                  int* __restrict__ rep,
                                                  int nN, int n, int e) {
    __shared__ int red[SCAN_B];
    int tid = threadIdx.x;
    int acc = 0;
    for (int j = tid; j < blockIdx.x; j += SCAN_B) acc += bsum[j];
    red[tid] = acc;
    __syncthreads();
    #pragma unroll
    for (int off = SCAN_B / 2; off >= 1; off >>= 1) {
        if (tid < off) red[tid] += red[tid + off];
        __syncthreads();
    }
    int base = red[0];
    int i = blockIdx.x * SCAN_B + tid;
    if (i < n) {
        int rp = row_ptr[i] + base;
        row_ptr[i] = rp;
        dinv[i] = rsqrtf((float)(deg[i] + 1));   // +1 self-loop
        #pragma unroll
        for (int r = 0; r < NREP; ++r) rep[r * nN + i] += rp;
    }
    if (i == 0) row_ptr[n] = e;
}

// Atomic-free scatter: col[rep[k][dst] + slot] = src.
__global__ void k_fill(const int* __restrict__ src, const int* __restrict__ dst,
                       const int* __restrict__ slot, const int* __restrict__ rep,
                       int* __restrict__ col, int nN, int e8, int e) {
    int i = blockIdx.x * blockDim.x + threadIdx.x;
    if (i < e8) {
        int4 v0 = ((const int4*)src)[2 * i];
        int4 v1 = ((const int4*)src)[2 * i + 1];
        int4 d0 = ((const int4*)dst)[2 * i];
        int4 d1 = ((const int4*)dst)[2 * i + 1];
        int4 s0 = ((const int4*)slot)[2 * i];
        int4 s1 = ((const int4*)slot)[2 * i + 1];
        col[rep[0 * nN + d0.x] + s0.x] = v0.x;
        col[rep[1 * nN + d0.y] + s0.y] = v0.y;
        col[rep[2 * nN + d0.z] + s0.z] = v0.z;
        col[rep[3 * nN + d0.w] + s0.w] = v0.w;
        col[rep[4 * nN + d1.x] + s1.x] = v1.x;
        col[rep[5 * nN + d1.y] + s1.y] = v1.y;
        col[rep[6 * nN + d1.z] + s1.z] = v1.z;
        col[rep[7 * nN + d1.w] + s1.w] = v1.w;
    }
    int base = e8 * 8;
    int t = blockIdx.x * blockDim.x + threadIdx.x;
    if (t < e - base) {
        int j = base + t;
        col[rep[(j & 7) * nN + dst[j]] + slot[j]] = src[j];
    }
}

// Cb[n,128](fp16, pi-permuted cols) = dinv[row] * (A[n,K] @ W[K,128]).
template<bool A32>
__global__ __launch_bounds__(256) void k_gemm_mfma(const void* __restrict__ Av,
                                                   const _Float16* __restrict__ Bsw,
                                                   _Float16* __restrict__ Cb,
                                                   const float* __restrict__ dinv,
                                                   int n, int K) {
    int tid   = threadIdx.x;
    int w     = tid >> 6;
    int ln    = tid & 63;
    int lane16 = ln & 15;
    int quad  = ln >> 4;
    int mrow  = blockIdx.x * 64 + w * 16 + lane16;
    int mload = mrow < n ? mrow : n - 1;
    int nchunk = K >> 5;

    floatx4 acc[8];
    #pragma unroll
    for (int t = 0; t < 8; ++t) acc[t] = (floatx4){0.f, 0.f, 0.f, 0.f};

    for (int c = 0; c < nchunk; ++c) {
        half8 a;
        if constexpr (A32) {
            const float* ap = (const float*)Av + (size_t)mload * K + c * 32 + quad * 8;
            float4 v0 = *(const float4*)ap;
            float4 v1 = *(const float4*)(ap + 4);
            a[0] = (_Float16)v0.x; a[1] = (_Float16)v0.y;
            a[2] = (_Float16)v0.z; a[3] = (_Float16)v0.w;
            a[4] = (_Float16)v1.x; a[5] = (_Float16)v1.y;
            a[6] = (_Float16)v1.z; a[7] = (_Float16)v1.w;
        } else {
            const _Float16* ap = (const _Float16*)Av + (size_t)mload * K + c * 32 + quad * 8;
            a = *(const half8*)ap;
        }
        const _Float16* bp = Bsw + ((size_t)(c * 8) * 64 + ln) * 8;
        #pragma unroll
        for (int t = 0; t < 8; ++t) {
            half8 b = *(const half8*)(bp + (size_t)t * 512);
            acc[t] = __builtin_amdgcn_mfma_f32_16x16x32_f16(a, b, acc[t], 0, 0, 0);
        }
    }

    int rbase = blockIdx.x * 64 + w * 16 + quad * 4;
    #pragma unroll
    for (int r = 0; r < 4; ++r) {
        int R = rbase + r;
        if (R < n) {
            float d = dinv[R];
            half8 o;
            #pragma unroll
            for (int t = 0; t < 8; ++t) o[t] = (_Float16)(acc[t][r] * d);
            *(half8*)(Cb + (size_t)R * 128 + lane16 * 8) = o;
        }
    }
}

// One wave per node; 16 lanes per row (dwordx4), 4 edges per load instr,
// x4 unroll = 16 rows in flight. shfl_xor butterfly combines the 4 groups.
// Lane (grp,pos): features at stored positions pos*8..pos*8+7.
template<bool OUT16>
__global__ __launch_bounds__(256) void k_agg(const _Float16* __restrict__ xwb,
                                             const float* __restrict__ dinv,
                                             const int* __restrict__ row_ptr,
                                             const int* __restrict__ col,
                                             const float* __restrict__ bp,
                                             void* __restrict__ hout, int n) {
    int wave = threadIdx.x >> 6;
    int ln   = threadIdx.x & 63;
    int grp  = ln >> 4;          // 0..3: which edge of each quad
    int pos  = ln & 15;          // 16B segment within the 256B row
    int i = blockIdx.x * 4 + wave;
    if (i >= n) return;
    int e0 = row_ptr[i], e1 = row_ptr[i + 1];

    const _Float16* xb = xwb + pos * 8;
    float acc[8];
    #pragma unroll
    for (int j = 0; j < 8; ++j) acc[j] = 0.f;

    int e = e0 + grp;
    for (; e + 12 < e1; e += 16) {   // 4 edges for this group in flight
        int s0 = col[e], s1 = col[e + 4], s2 = col[e + 8], s3 = col[e + 12];
        half8 u0 = *(const half8*)(xb + (size_t)s0 * 128);
        half8 u1 = *(const half8*)(xb + (size_t)s1 * 128);
        half8 u2 = *(const half8*)(xb + (size_t)s2 * 128);
        half8 u3 = *(const half8*)(xb + (size_t)s3 * 128);
        #pragma unroll
        for (int j = 0; j < 8; ++j)
            acc[j] += (float)u0[j] + (float)u1[j] + (float)u2[j] + (float)u3[j];
    }
    for (; e < e1; e += 4) {
        int s = col[e];
        half8 u = *(const half8*)(xb + (size_t)s * 128);
        #pragma unroll
        for (int j = 0; j < 8; ++j) acc[j] += (float)u[j];
    }

    // combine the 4 groups (lanes xor 16, xor 32)
    #pragma unroll
    for (int j = 0; j < 8; ++j) {
        acc[j] += __shfl_xor(acc[j], 16, 64);
        acc[j] += __shfl_xor(acc[j], 32, 64);
    }

    // self-loop + epilogue (all lanes compute; group 0 stores)
    half8 us = *(const half8*)(xb + (size_t)i * 128);
    float di = dinv[i];
    float4 bq0 = *(const float4*)(bp + pos * 8);
    float4 bq1 = *(const float4*)(bp + pos * 8 + 4);
    float bb[8] = {bq0.x, bq0.y, bq0.z, bq0.w, bq1.x, bq1.y, bq1.z, bq1.w};
    float ov[8];
    #pragma unroll
    for (int j = 0; j < 8; ++j)
        ov[j] = fmaxf(fmaf(di, acc[j] + (float)us[j], bb[j]), 0.f);

    if (grp == 0) {
        if constexpr (OUT16) {
            half8 o;
            #pragma unroll
            for (int j = 0; j < 8; ++j) o[j] = (_Float16)ov[j];
            *(half8*)((_Float16*)hout + (size_t)i * 128 + pos * 8) = o;
        } else {
            // position p = pos*8+j -> column j*16+pos (64B coalesced per j)
            float* hf = (float*)hout + (size_t)i * 128;
            #pragma unroll
            for (int j = 0; j < 8; ++j) hf[j * 16 + pos] = ov[j];
        }
    }
}

// out[n,16] = h2[n,128] @ Wc[128,16] + bc. (h2 fp32, un-permuted.)
__global__ __launch_bounds__(256) void k_out(const float* __restrict__ h2,
                                             const float* __restrict__ Wc,
                                             const float* __restrict__ bc,
                                             float* __restrict__ out, int n) {
    __shared__ float Ws[128 * 16];
    __shared__ float bs[16];
    __shared__ float hs[16][128];
    int tid = threadIdx.x;
    for (int t = tid; t < 128 * 16; t += 256) Ws[t] = Wc[t];
    if (tid < 16) bs[tid] = bc[tid];
    int r0 = blockIdx.x * 16;
    {
        int r = tid >> 4;
        int c = (tid & 15) * 8;
        int row = r0 + r;
        if (row < n) {
            const float* hp = h2 + (size_t)row * 128 + c;
            *(float4*)&hs[r][c]     = *(const float4*)hp;
            *(float4*)&hs[r][c + 4] = *(const float4*)(hp + 4);
        }
    }
    __syncthreads();
    int ti = tid >> 4, j = tid & 15;
    float acc = bs[j];
    #pragma unroll 8
    for (int k = 0; k < 128; ++k) acc = fmaf(hs[ti][k], Ws[k * 16 + j], acc);
    int row = r0 + ti;
    if (row < n) out[(size_t)row * 16 + j] = acc;
}

static inline size_t align256(size_t x) { return (x + 255) & ~(size_t)255; }

extern "C" void kernel_launch(void* const* d_in, const int* in_sizes, int n_in,
                              void* d_out, int out_size, void* d_ws, size_t ws_size,
                              hipStream_t stream) {
    const float* fts = (const float*)d_in[0];
    const int*   ei  = (const int*)d_in[1];
    const float* W1  = (const float*)d_in[2];
    const float* b1  = (const float*)d_in[3];
    const float* W2  = (const float*)d_in[4];
    const float* b2  = (const float*)d_in[5];
    const float* Wc  = (const float*)d_in[6];
    const float* bc  = (const float*)d_in[7];

    const int N = in_sizes[0] / IN_DIM;     // 50000
    const int E = in_sizes[1] / 2;          // 800000
    const int* src = ei;
    const int* dst = ei + E;

    char* p = (char*)d_ws;
    int* rep      = (int*)p;               p += align256(sizeof(int) * NREP * N);
    int* deg      = (int*)p;               p += align256(sizeof(int) * N);
    int* row_ptr  = (int*)p;               p += align256(sizeof(int) * (N + 1));
    float* dinv   = (float*)p;             p += align256(sizeof(float) * N);
    int* slot     = (int*)p;               p += align256(sizeof(int) * E);
    int* col      = (int*)p;               p += align256(sizeof(int) * E);
    int* bsum     = (int*)p;               p += align256(sizeof(int) * 512);
    _Float16* Bsw1 = (_Float16*)p;         p += align256(sizeof(_Float16) * IN_DIM * HID);
    _Float16* Bsw2 = (_Float16*)p;         p += align256(sizeof(_Float16) * HID * HID);
    float* bp1    = (float*)p;             p += align256(sizeof(float) * HID);
    float* bp2    = (float*)p;             p += align256(sizeof(float) * HID);
    _Float16* xwb = (_Float16*)p;          p += align256(sizeof(_Float16) * (size_t)N * HID);
    _Float16* h1  = (_Float16*)p;          p += align256(sizeof(_Float16) * (size_t)N * HID);

    float* out = (float*)d_out;                   // [N,16]
    float* h2  = (float*)d_out + (size_t)N * 16;  // [N,128]

    const int T = 256;
    const int E8 = E / 8;
    dim3 gE8((E8 + T - 1) / T);
    const int nScanB = (N + SCAN_B - 1) / SCAN_B;

    // Fused prep (rep zero + W swizzles + bias perms)
    const int nrepN = NREP * N;
    const int zr = (nrepN >> 2) + (nrepN & 3);
    const int prepTot = zr + IN_DIM * HID + HID * HID + 2 * HID;
    k_prep<<<(prepTot + T - 1) / T, T, 0, stream>>>(rep, nrepN, W1, Bsw1, W2, Bsw2,
                                                    b1, bp1, b2, bp2);
    // Graph structure
    k_count<<<gE8, T, 0, stream>>>(dst, rep, slot, N, E8, E);
    k_scan1<<<nScanB, SCAN_B, 0, stream>>>(rep, deg, row_ptr, bsum, N, N);
    k_scan3<<<nScanB, SCAN_B, 0, stream>>>(row_ptr, bsum, deg, dinv, rep, N, N, E);
    k_fill<<<gE8, T, 0, stream>>>(src, dst, slot, rep, col, N, E8, E);

    dim3 gGemm((N + 63) / 64);
    dim3 gAgg((N + 3) / 4);

    // Layer 1
    k_gemm_mfma<true><<<gGemm, T, 0, stream>>>(fts, Bsw1, xwb, dinv, N, IN_DIM);
    k_agg<true><<<gAgg, T, 0, stream>>>(xwb, dinv, row_ptr, col, bp1, h1, N);
    // Layer 2
    k_gemm_mfma<false><<<gGemm, T, 0, stream>>>(h1, Bsw2, xwb, dinv, N, HID);
    k_agg<false><<<gAgg, T, 0, stream>>>(xwb, dinv, row_ptr, col, bp2, h2, N);
    // Classifier
    k_out<<<(N + 15) / 16, T, 0, stream>>>(h2, Wc, bc, out, N);
}